// Round 2
// baseline (144.231 us; speedup 1.0000x reference)
//
#include <hip/hip_runtime.h>
#include <hip/hip_bf16.h>
#include <stdint.h>

// Problem constants (B, L, D, T) = (2, 2048, 1536, 2)
#define B_ 2
#define L_ 2048
#define D_ 1536

typedef __attribute__((ext_vector_type(4))) float  f32x4;
typedef __attribute__((ext_vector_type(8))) __bf16 bf16x8;

__device__ __forceinline__ unsigned short f2bf(float f) {
  unsigned int u = __float_as_uint(f);
  u += 0x7fffu + ((u >> 16) & 1u);   // RNE
  return (unsigned short)(u >> 16);
}

// ---------------------------------------------------------------------------
// Stage 1: hs(fp32) -> X(bf16), and P[t] = hs * Wp[t] (bf16), t in {0,1}
// (unchanged: ~63 MB of traffic, near its HBM floor)
// ---------------------------------------------------------------------------
__global__ __launch_bounds__(256) void conv_kernel(
    const float* __restrict__ hs, const float* __restrict__ W,
    unsigned short* __restrict__ X, unsigned short* __restrict__ P) {
  const int idx  = blockIdx.x * 256 + threadIdx.x;
  const int base = idx * 4;
  const int d    = base % D_;
  const float4 h  = *(const float4*)(hs + base);
  const float4 w0 = *(const float4*)(W + d);
  const float4 w1 = *(const float4*)(W + 2 * D_ + d);
  ushort4 x, p0, p1;
  x.x  = f2bf(h.x);        x.y  = f2bf(h.y);        x.z  = f2bf(h.z);        x.w  = f2bf(h.w);
  p0.x = f2bf(h.x * w0.x); p0.y = f2bf(h.y * w0.y); p0.z = f2bf(h.z * w0.z); p0.w = f2bf(h.w * w0.w);
  p1.x = f2bf(h.x * w1.x); p1.y = f2bf(h.y * w1.y); p1.z = f2bf(h.z * w1.z); p1.w = f2bf(h.w * w1.w);
  *(ushort4*)(X + base) = x;
  *(ushort4*)(P + base) = p0;
  *(ushort4*)(P + (size_t)B_ * L_ * D_ + base) = p1;
}

// ---------------------------------------------------------------------------
// Stage 2: 256x256 block, 4 waves x (128x128) register tiles, BK=64 dbuf.
// LDS-read amplification = 1 (each staged element read by exactly one wave):
// 128 KB reads + 64 KB writes per K-tile per CU (was 224+64 with 8 waves).
// One vmcnt(0)+barrier per K-tile; stage issued a full COMPUTE (~1500 cyc)
// before its wait, so the drain is covered.
// M-order of the A region: [t0 i0-63 | t1 i0-63 | t0 i64-127 | t1 i64-127]
// so wave wr holds (t0,t1) for the same i rows -> dense float2 epilogue.
// acc = 8x8 f32x4 = 256 VGPR; __launch_bounds__(256,1) for the 512 budget.
// ---------------------------------------------------------------------------
__device__ __forceinline__ void gload16(const unsigned short* g, unsigned short* l) {
  __builtin_amdgcn_global_load_lds(
      (const __attribute__((address_space(1))) unsigned int*)g,
      (__attribute__((address_space(3))) unsigned int*)l, 16, 0, 0);
}

__global__ __launch_bounds__(256, 1) void gemm_kernel(
    const unsigned short* __restrict__ X, const unsigned short* __restrict__ P,
    const float* __restrict__ bias, float2* __restrict__ out) {
  __shared__ unsigned short lds[65536];   // 128 KiB: 2 buffers x (A 32K + B 32K)

  const int tid = threadIdx.x;

  // ---- T1: XCD-aware bijective swizzle (256 % 8 == 0)
  const int id  = blockIdx.x;
  const int swz = (id & 7) * 32 + (id >> 3);
  const int bz  = swz >> 7;               // batch
  const int t2  = swz & 127;
  const int I0  = (t2 >> 3) * 128;        // 16 i-tiles of 128
  const int J0  = (t2 & 7) * 256;         // 8 j-tiles of 256

  const size_t planeB = (size_t)B_ * L_ * D_;

  // ---- staging geometry: thread t, row sr = t>>3 within a 32-row slab,
  // stored chunk t&7 holds logical chunk (t&7)^(sr&7) (inverse of read XOR).
  const int    sr    = tid >> 3;
  const int    sc    = (tid & 7) ^ (sr & 7);
  const size_t lgoff = (size_t)sr * D_ + (size_t)(sc * 8);
  const int    w     = tid >> 6;

  // A sub-regions s = ih*2 + t  (ih = i-half, t = plane), 64 rows each
  const unsigned short* gA0 = P +          ((size_t)(bz * L_ + I0)) * D_ + lgoff;      // ih0,t0
  const unsigned short* gA1 = P + planeB + ((size_t)(bz * L_ + I0)) * D_ + lgoff;      // ih0,t1
  const unsigned short* gA2 = P +          ((size_t)(bz * L_ + I0 + 64)) * D_ + lgoff; // ih1,t0
  const unsigned short* gA3 = P + planeB + ((size_t)(bz * L_ + I0 + 64)) * D_ + lgoff; // ih1,t1
  const unsigned short* gB  = X +          ((size_t)(bz * L_ + J0)) * D_ + lgoff;

  // ---- compute geometry: 4 waves as 2x2, per-wave 128(M) x 128(N)
  const int lane = tid & 63;
  const int wr   = w >> 1;
  const int wc   = w & 1;
  const int lr   = lane & 15;
  const int q    = lane >> 4;
  const int swd  = lr & 7;
  const int csw0 = ((0 + q) ^ swd) * 8;   // kk=0 chunk, swizzled (shorts)
  const int csw1 = ((4 + q) ^ swd) * 8;   // kk=1
  const int aBase = (wr * 128 + lr) * 64;           // A region row base (shorts)
  const int bBase = 16384 + (wc * 128 + lr) * 64;   // B region row base

  f32x4 acc[8][8] = {};

#define STG(NB, KT)                                                            \
  do {                                                                         \
    const size_t ko = (size_t)(KT) * 64;                                       \
    gload16(gA0 + ko,                    lds + (NB) + (0 * 64 + 0 * 32 + w * 8) * 64); \
    gload16(gA0 + ko + (size_t)32 * D_,  lds + (NB) + (0 * 64 + 1 * 32 + w * 8) * 64); \
    gload16(gA1 + ko,                    lds + (NB) + (1 * 64 + 0 * 32 + w * 8) * 64); \
    gload16(gA1 + ko + (size_t)32 * D_,  lds + (NB) + (1 * 64 + 1 * 32 + w * 8) * 64); \
    gload16(gA2 + ko,                    lds + (NB) + (2 * 64 + 0 * 32 + w * 8) * 64); \
    gload16(gA2 + ko + (size_t)32 * D_,  lds + (NB) + (2 * 64 + 1 * 32 + w * 8) * 64); \
    gload16(gA3 + ko,                    lds + (NB) + (3 * 64 + 0 * 32 + w * 8) * 64); \
    gload16(gA3 + ko + (size_t)32 * D_,  lds + (NB) + (3 * 64 + 1 * 32 + w * 8) * 64); \
    _Pragma("unroll") for (int l = 0; l < 8; ++l)                              \
      gload16(gB + ko + (size_t)(l * 32) * D_,                                 \
              lds + (NB) + 16384 + (l * 32 + w * 8) * 64);                     \
  } while (0)

#define COMPUTE(CB)                                                            \
  do {                                                                         \
    _Pragma("unroll") for (int kk = 0; kk < 2; ++kk) {                         \
      const int cs = kk ? csw1 : csw0;                                         \
      bf16x8 aF[8], bF[8];                                                     \
      _Pragma("unroll") for (int m = 0; m < 8; ++m)                            \
        aF[m] = *(const bf16x8*)(lds + (CB) + aBase + m * 1024 + cs);          \
      _Pragma("unroll") for (int n = 0; n < 8; ++n)                            \
        bF[n] = *(const bf16x8*)(lds + (CB) + bBase + n * 1024 + cs);          \
      _Pragma("unroll") for (int m = 0; m < 8; ++m)                            \
        _Pragma("unroll") for (int n = 0; n < 8; ++n)                          \
          acc[m][n] = __builtin_amdgcn_mfma_f32_16x16x32_bf16(                 \
              aF[m], bF[n], acc[m][n], 0, 0, 0);                               \
    }                                                                          \
  } while (0)

  // ---- prologue: K-tile 0 into buffer 0
  STG(0, 0);
  asm volatile("s_waitcnt vmcnt(0)" ::: "memory");
  __builtin_amdgcn_s_barrier();

  // ---- main loop: one vmcnt(0)+barrier per K-tile
#pragma unroll 1
  for (int kt = 0; kt < 24; ++kt) {
    const int cb = (kt & 1) * 32768;
    if (kt < 23) STG(32768 - cb, kt + 1);
    COMPUTE(cb);
    if (kt < 23) {
      asm volatile("s_waitcnt vmcnt(0)" ::: "memory");
      __builtin_amdgcn_s_barrier();
    }
  }
#undef STG
#undef COMPUTE

  // ---- epilogue: C/D layout col(j)=lane&15, row(i)=q*4+reg.
  // acc[m][.] (m<4) = t0, acc[m+4][.] = t1 at the SAME i -> dense float2.
  const float bias0 = bias[0], bias1 = bias[1];
#pragma unroll
  for (int m = 0; m < 4; ++m) {
#pragma unroll
    for (int r = 0; r < 4; ++r) {
      const int i = I0 + wr * 64 + m * 16 + q * 4 + r;
      float2* orow = out + (size_t)(bz * L_ + i) * L_ + (J0 + wc * 128 + lr);
#pragma unroll
      for (int n = 0; n < 8; ++n) {
        float2 v;
        v.x = acc[m][n][r] + bias0;
        v.y = acc[m + 4][n][r] + bias1;
        orow[n * 16] = v;
      }
    }
  }
}

extern "C" void kernel_launch(void* const* d_in, const int* in_sizes, int n_in,
                              void* d_out, int out_size, void* d_ws, size_t ws_size,
                              hipStream_t stream) {
  const float* hs   = (const float*)d_in[0];
  const float* W    = (const float*)d_in[1];
  const float* bias = (const float*)d_in[2];

  unsigned short* X = (unsigned short*)d_ws;                 // B*L*D bf16
  unsigned short* P = X + (size_t)B_ * L_ * D_;              // T*B*L*D bf16

  const int nconv = (B_ * L_ * D_ / 4) / 256;                // 6144 blocks
  conv_kernel<<<nconv, 256, 0, stream>>>(hs, W, X, P);

  gemm_kernel<<<256, 256, 0, stream>>>(X, P, bias, (float2*)d_out);
}

// Round 4
// 142.824 us; speedup vs baseline: 1.0098x; 1.0098x over previous
//
#include <hip/hip_runtime.h>
#include <hip/hip_bf16.h>
#include <stdint.h>

// Problem constants (B, L, D, T) = (2, 2048, 1536, 2)
#define B_ 2
#define L_ 2048
#define D_ 1536

typedef __attribute__((ext_vector_type(4)))  float  f32x4;
typedef __attribute__((ext_vector_type(16))) float  f32x16;
typedef __attribute__((ext_vector_type(8)))  __bf16 bf16x8;

__device__ __forceinline__ unsigned short f2bf(float f) {
  unsigned int u = __float_as_uint(f);
  u += 0x7fffu + ((u >> 16) & 1u);   // RNE
  return (unsigned short)(u >> 16);
}

// ---------------------------------------------------------------------------
// Stage 1: hs(fp32) -> X(bf16), and P[t] = hs * Wp[t] (bf16), t in {0,1}
// ---------------------------------------------------------------------------
__global__ __launch_bounds__(256) void conv_kernel(
    const float* __restrict__ hs, const float* __restrict__ W,
    unsigned short* __restrict__ X, unsigned short* __restrict__ P) {
  const int idx  = blockIdx.x * 256 + threadIdx.x;
  const int base = idx * 4;
  const int d    = base % D_;
  const float4 h  = *(const float4*)(hs + base);
  const float4 w0 = *(const float4*)(W + d);
  const float4 w1 = *(const float4*)(W + 2 * D_ + d);
  ushort4 x, p0, p1;
  x.x  = f2bf(h.x);        x.y  = f2bf(h.y);        x.z  = f2bf(h.z);        x.w  = f2bf(h.w);
  p0.x = f2bf(h.x * w0.x); p0.y = f2bf(h.y * w0.y); p0.z = f2bf(h.z * w0.z); p0.w = f2bf(h.w * w0.w);
  p1.x = f2bf(h.x * w1.x); p1.y = f2bf(h.y * w1.y); p1.z = f2bf(h.z * w1.z); p1.w = f2bf(h.w * w1.w);
  *(ushort4*)(X + base) = x;
  *(ushort4*)(P + base) = p0;
  *(ushort4*)(P + (size_t)B_ * L_ * D_ + base) = p1;
}

// ---------------------------------------------------------------------------
// Stage 2: 256x256 8-phase GEMM, t fused along M — round-1 structure with the
// MFMA shape switched 16x16x32 -> 32x32x16 (2495 vs 2176 TF pipe ceiling,
// half the MFMA instruction count; identical LDS reads, identical 248-reg
// footprint => still 2 waves/SIMD). Staging, vmcnt ledger, XOR swizzle all
// byte-identical to round 1 (57.4 us baseline).
// ---------------------------------------------------------------------------
__device__ __forceinline__ void gload16(const unsigned short* g, unsigned short* l) {
  __builtin_amdgcn_global_load_lds(
      (const __attribute__((address_space(1))) unsigned int*)g,
      (__attribute__((address_space(3))) unsigned int*)l, 16, 0, 0);
}

#define A0OFF 0
#define A1OFF 8192
#define B0OFF 16384
#define B1OFF 24576

__global__ __launch_bounds__(512, 2) void gemm_kernel(
    const unsigned short* __restrict__ X, const unsigned short* __restrict__ P,
    const float* __restrict__ bias, float2* __restrict__ out) {
  __shared__ unsigned short lds[65536];   // 128 KiB

  const int tid = threadIdx.x;

  // ---- T1: XCD-aware bijective swizzle (256 % 8 == 0)
  const int id  = blockIdx.x;
  const int swz = (id & 7) * 32 + (id >> 3);
  const int bz  = swz >> 7;               // batch
  const int t2  = swz & 127;
  const int I0  = (t2 >> 3) * 128;        // 16 i-tiles
  const int J0  = (t2 & 7) * 256;         // 8 j-tiles

  const size_t planeB = (size_t)B_ * L_ * D_;
  const unsigned short* gA0 = P + (size_t)(bz * L_ + I0) * D_;   // P0 rows
  const unsigned short* gA1 = gA0 + planeB;                      // P1 rows
  const unsigned short* gB0 = X + (size_t)(bz * L_ + J0) * D_;   // X rows
  const unsigned short* gB1 = gB0 + (size_t)128 * D_;

  // ---- staging geometry (identical to round 1): thread t, load l in {0,1}:
  // within-half row r = l*64 + (t>>3); stored chunk t&7 holds logical chunk
  // (t&7)^(r&7) (inverse of the read-side XOR swizzle).
  const int    sr    = tid >> 3;
  const int    sc    = (tid & 7) ^ (sr & 7);
  const size_t lgoff = (size_t)sr * D_ + (size_t)(sc * 8);
  const int    wuni  = (tid >> 6) * 512;   // wave-uniform LDS base (shorts)

  // ---- compute geometry (32x32x16 fragments)
  const int lane = tid & 63;
  const int w    = tid >> 6;
  const int wr   = w & 1;        // 2 wave M-strips of 64 rows
  const int wc   = w >> 1;       // 4 wave col-slices of 32
  const int l31  = lane & 31;
  const int q2   = lane >> 5;
  const int swd7 = lane & 7;     // == row&7 for all fragment rows
  int csw32[4];
#pragma unroll
  for (int ks = 0; ks < 4; ++ks) csw32[ks] = ((ks * 2 + q2) ^ swd7) * 8;
  int aRow32[2];
#pragma unroll
  for (int m = 0; m < 2; ++m) aRow32[m] = (wr * 64 + m * 32 + l31) * 64;
  const int bRow32 = (wc * 32 + l31) * 64;

  f32x16 acc32[2][2][2] = {};   // [plane t][m32][NH] — 128 regs
  bf16x8 aF[2][4], bF[4];

#define STG(REG, GBASE, KTN)                                                  \
  do {                                                                        \
    const unsigned short* g0 = (GBASE) + lgoff + (size_t)((KTN) * 64);        \
    gload16(g0,                   lds + (REG) + wuni);                        \
    gload16(g0 + (size_t)64 * D_, lds + (REG) + 4096 + wuni);                 \
  } while (0)

#define RDA32(CB, PL)                                                         \
  do {                                                                        \
    _Pragma("unroll") for (int m = 0; m < 2; ++m)                             \
      _Pragma("unroll") for (int ks = 0; ks < 4; ++ks)                        \
        aF[m][ks] = *(const bf16x8*)(lds + (CB) + (PL) * 8192 +               \
                                     aRow32[m] + csw32[ks]);                  \
  } while (0)

#define RDB32(CB, NH)                                                         \
  do {                                                                        \
    _Pragma("unroll") for (int ks = 0; ks < 4; ++ks)                          \
      bF[ks] = *(const bf16x8*)(lds + (CB) + 16384 + (NH) * 8192 +            \
                                bRow32 + csw32[ks]);                          \
  } while (0)

#define MM32(PL, NH)                                                          \
  do {                                                                        \
    _Pragma("unroll") for (int ks = 0; ks < 4; ++ks)                          \
      _Pragma("unroll") for (int m = 0; m < 2; ++m)                           \
        acc32[PL][m][NH] = __builtin_amdgcn_mfma_f32_32x32x16_bf16(           \
            aF[m][ks], bF[ks], acc32[PL][m][NH], 0, 0, 0);                    \
  } while (0)

#define BAR()   __builtin_amdgcn_s_barrier()
#define LGKM0() asm volatile("s_waitcnt lgkmcnt(0)" ::: "memory")
#define WVM(n)  asm volatile("s_waitcnt vmcnt(" #n ")" ::: "memory")
#define PRIO1() __builtin_amdgcn_s_setprio(1)
#define PRIO0() __builtin_amdgcn_s_setprio(0)

  // Phase order per K-tile: Q(0,0) Q(0,1) Q(1,1) Q(1,0).
  // Stage of kt+1 (into NB): A0,B0 @p0 ; B1 @p1 ; A1 @p2 ; - @p3.
#define KSTEP(CB, NB, KTN)                                                    \
  do {                                                                        \
    /* p0 */                                                                  \
    RDA32(CB, 0); RDB32(CB, 0);                                               \
    STG((NB) + A0OFF, gA0, KTN); STG((NB) + B0OFF, gB0, KTN);                 \
    BAR(); LGKM0();                                                           \
    PRIO1(); MM32(0, 0); PRIO0();                                             \
    WVM(6); BAR();                                                            \
    /* p1 */                                                                  \
    RDB32(CB, 1);                                                             \
    STG((NB) + B1OFF, gB1, KTN);                                              \
    BAR(); LGKM0();                                                           \
    PRIO1(); MM32(0, 1); PRIO0();                                             \
    WVM(6); BAR();                                                            \
    /* p2 */                                                                  \
    RDA32(CB, 1);                                                             \
    STG((NB) + A1OFF, gA1, KTN);                                              \
    BAR(); LGKM0();                                                           \
    PRIO1(); MM32(1, 1); PRIO0();                                             \
    BAR();                                                                    \
    /* p3 (B-half0 re-read; no staging) */                                    \
    RDB32(CB, 0);                                                             \
    BAR(); LGKM0();                                                           \
    PRIO1(); MM32(1, 0); PRIO0();                                             \
    WVM(4); BAR();                                                            \
  } while (0)

#define KTAIL(CB)                                                             \
  do {                                                                        \
    RDA32(CB, 0); RDB32(CB, 0);                                               \
    BAR(); LGKM0();                                                           \
    PRIO1(); MM32(0, 0); PRIO0();                                             \
    WVM(2); BAR();                                                            \
    RDB32(CB, 1);                                                             \
    BAR(); LGKM0();                                                           \
    PRIO1(); MM32(0, 1); PRIO0();                                             \
    WVM(0); BAR();                                                            \
    RDA32(CB, 1);                                                             \
    BAR(); LGKM0();                                                           \
    PRIO1(); MM32(1, 1); PRIO0();                                             \
    BAR();                                                                    \
    RDB32(CB, 0);                                                             \
    LGKM0();                                                                  \
    PRIO1(); MM32(1, 0); PRIO0();                                             \
  } while (0)

  // ---- prologue: K-tile 0 into buffer 0, issued in wait-order
  STG(A0OFF, gA0, 0); STG(B0OFF, gB0, 0);
  STG(B1OFF, gB1, 0);
  STG(A1OFF, gA1, 0);
  WVM(4); BAR();

  // ---- main loop: kt = 0..21 (paired), 22 (stages 23), tail 23
#pragma unroll 1
  for (int it = 0; it < 11; ++it) {
    const int kt0 = 2 * it;
    KSTEP(0,     32768, kt0 + 1);
    KSTEP(32768, 0,     kt0 + 2);
  }
  KSTEP(0, 32768, 23);
  KTAIL(32768);

#undef KSTEP
#undef KTAIL
#undef STG
#undef RDA32
#undef RDB32
#undef MM32

  // ---- epilogue: 32x32 C/D layout col(j)=lane&31, row=(r&3)+8*(r>>2)+4*q2.
  // acc32[0][..] = t0, acc32[1][..] = t1 at the SAME i -> dense float2.
  const float bias0 = bias[0], bias1 = bias[1];
#pragma unroll
  for (int m = 0; m < 2; ++m) {
#pragma unroll
    for (int NH = 0; NH < 2; ++NH) {
      const int j = J0 + NH * 128 + wc * 32 + l31;
#pragma unroll
      for (int r = 0; r < 16; ++r) {
        const int i = I0 + wr * 64 + m * 32 + (r & 3) + 8 * (r >> 2) + 4 * q2;
        float2 v;
        v.x = acc32[0][m][NH][r] + bias0;
        v.y = acc32[1][m][NH][r] + bias1;
        out[(size_t)(bz * L_ + i) * L_ + j] = v;
      }
    }
  }
}

extern "C" void kernel_launch(void* const* d_in, const int* in_sizes, int n_in,
                              void* d_out, int out_size, void* d_ws, size_t ws_size,
                              hipStream_t stream) {
  const float* hs   = (const float*)d_in[0];
  const float* W    = (const float*)d_in[1];
  const float* bias = (const float*)d_in[2];

  unsigned short* X = (unsigned short*)d_ws;                 // B*L*D bf16
  unsigned short* P = X + (size_t)B_ * L_ * D_;              // T*B*L*D bf16

  const int nconv = (B_ * L_ * D_ / 4) / 256;                // 6144 blocks
  conv_kernel<<<nconv, 256, 0, stream>>>(hs, W, X, P);

  gemm_kernel<<<256, 512, 0, stream>>>(X, P, bias, (float2*)d_out);
}

// Round 7
// 139.886 us; speedup vs baseline: 1.0311x; 1.0210x over previous
//
#include <hip/hip_runtime.h>
#include <hip/hip_bf16.h>
#include <stdint.h>

// Problem constants (B, L, D, T) = (2, 2048, 1536, 2)
#define B_ 2
#define L_ 2048
#define D_ 1536

typedef __attribute__((ext_vector_type(4))) float  f32x4;
typedef __attribute__((ext_vector_type(8))) __bf16 bf16x8;

__device__ __forceinline__ unsigned short f2bf(float f) {
  unsigned int u = __float_as_uint(f);
  u += 0x7fffu + ((u >> 16) & 1u);   // RNE
  return (unsigned short)(u >> 16);
}

// ---------------------------------------------------------------------------
// Stage 1: hs(fp32) -> X(bf16), and P[t] = hs * Wp[t] (bf16), t in {0,1}
// ---------------------------------------------------------------------------
__global__ __launch_bounds__(256) void conv_kernel(
    const float* __restrict__ hs, const float* __restrict__ W,
    unsigned short* __restrict__ X, unsigned short* __restrict__ P) {
  const int idx  = blockIdx.x * 256 + threadIdx.x;
  const int base = idx * 4;
  const int d    = base % D_;
  const float4 h  = *(const float4*)(hs + base);
  const float4 w0 = *(const float4*)(W + d);
  const float4 w1 = *(const float4*)(W + 2 * D_ + d);
  ushort4 x, p0, p1;
  x.x  = f2bf(h.x);        x.y  = f2bf(h.y);        x.z  = f2bf(h.z);        x.w  = f2bf(h.w);
  p0.x = f2bf(h.x * w0.x); p0.y = f2bf(h.y * w0.y); p0.z = f2bf(h.z * w0.z); p0.w = f2bf(h.w * w0.w);
  p1.x = f2bf(h.x * w1.x); p1.y = f2bf(h.y * w1.y); p1.z = f2bf(h.z * w1.z); p1.w = f2bf(h.w * w1.w);
  *(ushort4*)(X + base) = x;
  *(ushort4*)(P + base) = p0;
  *(ushort4*)(P + (size_t)B_ * L_ * D_ + base) = p1;
}

// ---------------------------------------------------------------------------
// Stage 2: 256x256 tile, t fused along M, K-HALF-phased schedule.
// Per K-tile (BK=64): 2 phases (kk=0,1). Each phase reads ALL 12 fragments
// at that kk (8 aF + 4 bF ds_read_b128, each staged byte read exactly once:
// 24 reads/wave/tile vs round-1's 28) and runs all 32 MFMAs.
// LDS: 2 buffers x 8 sub-blocks (A0,A1,B0,B1 x klo,khi), each 8 KB =
// exactly one global_load_lds per thread; row stride 64 B; stored slot =
// chunk ^ ((row>>1)&3) (involution: pre-swizzled source, swizzled read).
// Ledger: p0 stages klo(kt+1), p1 stages khi(kt+1); end-p0 vmcnt(4) ->
// khi(kt) ready for p1; end-p1 vmcnt(4) -> klo(kt+1) ready. Never drains.
// 4 barriers + 2 waits per tile (vs 8 + 3). Epilogue = round-1 verbatim
// (round-5 crash was an epilogue index bug: wc*128 vs wc*32 -> OOB).
// ---------------------------------------------------------------------------
__device__ __forceinline__ void gload16(const unsigned short* g, unsigned short* l) {
  __builtin_amdgcn_global_load_lds(
      (const __attribute__((address_space(1))) unsigned int*)g,
      (__attribute__((address_space(3))) unsigned int*)l, 16, 0, 0);
}

__global__ __launch_bounds__(512, 2) void gemm_kernel(
    const unsigned short* __restrict__ X, const unsigned short* __restrict__ P,
    const float* __restrict__ bias, float2* __restrict__ out) {
  __shared__ unsigned short lds[65536];   // 128 KiB = 2 buffers x 32768 shorts

  const int tid = threadIdx.x;

  // ---- T1: XCD-aware bijective swizzle (256 % 8 == 0)
  const int id  = blockIdx.x;
  const int swz = (id & 7) * 32 + (id >> 3);
  const int bz  = swz >> 7;               // batch
  const int t2  = swz & 127;
  const int I0  = (t2 >> 3) * 128;        // 16 i-tiles
  const int J0  = (t2 & 7) * 256;         // 8 j-tiles

  const size_t planeB = (size_t)B_ * L_ * D_;

  // ---- staging: thread tid -> sub-block entry (row r = tid>>2, slot tid&3),
  // 16B each, LDS-linear (dest = base + lane*16). Source chunk is the
  // inverse-swizzled c = (tid&3) ^ ((r>>1)&3) = (tid&3) ^ ((tid>>3)&3).
  const size_t gsrcOff = (size_t)(tid >> 2) * D_ +
                         (size_t)((((tid & 3) ^ ((tid >> 3) & 3))) * 8);
  const unsigned short* sA0 = P + (size_t)(bz * L_ + I0) * D_ + gsrcOff;   // P0
  const unsigned short* sA1 = sA0 + planeB;                                // P1
  const unsigned short* sB0 = X + (size_t)(bz * L_ + J0) * D_ + gsrcOff;   // X lo
  const unsigned short* sB1 = sB0 + (size_t)128 * D_;                      // X hi
  const int wuni = (tid >> 6) * 512;   // wave-uniform LDS base (shorts)

  // ---- compute geometry (16x16x32 frags; 8 waves = 2 wr x 4 wc)
  const int lane = tid & 63;
  const int w    = tid >> 6;
  const int wr   = w & 1;
  const int wc   = w >> 1;
  const int lr   = lane & 15;
  const int q    = lane >> 4;
  const int slot8 = ((q ^ ((lr >> 1) & 3)) * 8);   // read-side swizzled slot
  int aOff[8], bOff[4];
#pragma unroll
  for (int m = 0; m < 8; ++m)
    aOff[m] = (m >> 2) * 4096 + (wr * 64 + (m & 3) * 16 + lr) * 32;
#pragma unroll
  for (int n = 0; n < 4; ++n)
    bOff[n] = 8192 + (n >> 1) * 4096 + (wc * 32 + (n & 1) * 16 + lr) * 32;

  f32x4  acc[8][4] = {};
  bf16x8 aF[8], bF[4];

  // Sub-block LDS offsets (shorts): buffer NB + KH*16384 + {A0:0, A1:4096,
  // B0:8192, B1:12288}; each sub-block = 4096 shorts = 8 KB = 128 rows x 64 B.
#define STG4(NB, KH, KTN)                                                     \
  do {                                                                        \
    const size_t ko = (size_t)((KTN) * 64 + (KH) * 32);                       \
    gload16(sA0 + ko, lds + (NB) + (KH) * 16384 + 0     + wuni);              \
    gload16(sA1 + ko, lds + (NB) + (KH) * 16384 + 4096  + wuni);              \
    gload16(sB0 + ko, lds + (NB) + (KH) * 16384 + 8192  + wuni);              \
    gload16(sB1 + ko, lds + (NB) + (KH) * 16384 + 12288 + wuni);              \
  } while (0)

#define RDALL(CB, KH)                                                         \
  do {                                                                        \
    const unsigned short* base_ = lds + (CB) + (KH) * 16384 + slot8;          \
    _Pragma("unroll") for (int m = 0; m < 8; ++m)                             \
      aF[m] = *(const bf16x8*)(base_ + aOff[m]);                              \
    _Pragma("unroll") for (int n = 0; n < 4; ++n)                             \
      bF[n] = *(const bf16x8*)(base_ + bOff[n]);                              \
  } while (0)

#define MMALL()                                                               \
  do {                                                                        \
    _Pragma("unroll") for (int m = 0; m < 8; ++m)                             \
      _Pragma("unroll") for (int n = 0; n < 4; ++n)                           \
        acc[m][n] = __builtin_amdgcn_mfma_f32_16x16x32_bf16(                  \
            aF[m], bF[n], acc[m][n], 0, 0, 0);                                \
  } while (0)

#define BAR()   __builtin_amdgcn_s_barrier()
#define LGKM0() asm volatile("s_waitcnt lgkmcnt(0)" ::: "memory")
#define WVM(n)  asm volatile("s_waitcnt vmcnt(" #n ")" ::: "memory")
#define PRIO1() __builtin_amdgcn_s_setprio(1)
#define PRIO0() __builtin_amdgcn_s_setprio(0)

#define KSTEP(CB, NB, KTN)                                                    \
  do {                                                                        \
    /* p0: kk=0 */                                                            \
    RDALL(CB, 0); STG4(NB, 0, KTN);                                           \
    BAR(); LGKM0();                                                           \
    PRIO1(); MMALL(); PRIO0();                                                \
    WVM(4); BAR();                                                            \
    /* p1: kk=1 */                                                            \
    RDALL(CB, 1); STG4(NB, 1, KTN);                                           \
    BAR(); LGKM0();                                                           \
    PRIO1(); MMALL(); PRIO0();                                                \
    WVM(4); BAR();                                                            \
  } while (0)

#define KTAIL(CB)                                                             \
  do {                                                                        \
    RDALL(CB, 0);                                                             \
    BAR(); LGKM0();                                                           \
    PRIO1(); MMALL(); PRIO0();                                                \
    WVM(0); BAR();                                                            \
    RDALL(CB, 1);                                                             \
    LGKM0();                                                                  \
    PRIO1(); MMALL(); PRIO0();                                                \
  } while (0)

  // ---- prologue: K-tile 0 (klo then khi) into buffer 0
  STG4(0, 0, 0);
  STG4(0, 1, 0);
  WVM(4); BAR();   // klo ready; khi drains at end of kt0-p0's WVM(4)

  // ---- main loop: kt = 0..21 (paired), 22 (stages 23), tail 23
#pragma unroll 1
  for (int it = 0; it < 11; ++it) {
    const int kt0 = 2 * it;
    KSTEP(0,     32768, kt0 + 1);
    KSTEP(32768, 0,     kt0 + 2);
  }
  KSTEP(0, 32768, 23);
  KTAIL(32768);

#undef KSTEP
#undef KTAIL
#undef STG4
#undef RDALL
#undef MMALL

  // ---- epilogue (VERBATIM round-1): C/D col(j)=lane&15, row(i)=q*4+reg.
  // acc[m][.] (m<4) = t0, acc[m+4][.] = t1 at the SAME i -> dense float2.
  const float bias0 = bias[0], bias1 = bias[1];
#pragma unroll
  for (int m = 0; m < 4; ++m) {
#pragma unroll
    for (int r = 0; r < 4; ++r) {
      const int i = I0 + wr * 64 + m * 16 + q * 4 + r;
      float2* orow = out + (size_t)(bz * L_ + i) * L_;
#pragma unroll
      for (int n = 0; n < 4; ++n) {
        const int j = J0 + (n >> 1) * 128 + wc * 32 + (n & 1) * 16 + lr;
        float2 v;
        v.x = acc[m][n][r] + bias0;
        v.y = acc[m + 4][n][r] + bias1;
        orow[j] = v;
      }
    }
  }
}

extern "C" void kernel_launch(void* const* d_in, const int* in_sizes, int n_in,
                              void* d_out, int out_size, void* d_ws, size_t ws_size,
                              hipStream_t stream) {
  const float* hs   = (const float*)d_in[0];
  const float* W    = (const float*)d_in[1];
  const float* bias = (const float*)d_in[2];

  unsigned short* X = (unsigned short*)d_ws;                 // B*L*D bf16
  unsigned short* P = X + (size_t)B_ * L_ * D_;              // T*B*L*D bf16

  const int nconv = (B_ * L_ * D_ / 4) / 256;                // 6144 blocks
  conv_kernel<<<nconv, 256, 0, stream>>>(hs, W, X, P);

  gemm_kernel<<<256, 512, 0, stream>>>(X, P, bias, (float2*)d_out);
}

// Round 8
// 136.452 us; speedup vs baseline: 1.0570x; 1.0252x over previous
//
#include <hip/hip_runtime.h>
#include <hip/hip_bf16.h>
#include <stdint.h>

// Problem constants (B, L, D, T) = (2, 2048, 1536, 2)
#define B_ 2
#define L_ 2048
#define D_ 1536

typedef __attribute__((ext_vector_type(4))) float  f32x4;
typedef __attribute__((ext_vector_type(8))) __bf16 bf16x8;

__device__ __forceinline__ unsigned short f2bf(float f) {
  unsigned int u = __float_as_uint(f);
  u += 0x7fffu + ((u >> 16) & 1u);   // RNE
  return (unsigned short)(u >> 16);
}

// ---------------------------------------------------------------------------
// Stage 1: hs(fp32) -> X(bf16), and P[t] = hs * Wp[t] (bf16), t in {0,1}
// ---------------------------------------------------------------------------
__global__ __launch_bounds__(256) void conv_kernel(
    const float* __restrict__ hs, const float* __restrict__ W,
    unsigned short* __restrict__ X, unsigned short* __restrict__ P) {
  const int idx  = blockIdx.x * 256 + threadIdx.x;
  const int base = idx * 4;
  const int d    = base % D_;
  const float4 h  = *(const float4*)(hs + base);
  const float4 w0 = *(const float4*)(W + d);
  const float4 w1 = *(const float4*)(W + 2 * D_ + d);
  ushort4 x, p0, p1;
  x.x  = f2bf(h.x);        x.y  = f2bf(h.y);        x.z  = f2bf(h.z);        x.w  = f2bf(h.w);
  p0.x = f2bf(h.x * w0.x); p0.y = f2bf(h.y * w0.y); p0.z = f2bf(h.z * w0.z); p0.w = f2bf(h.w * w0.w);
  p1.x = f2bf(h.x * w1.x); p1.y = f2bf(h.y * w1.y); p1.z = f2bf(h.z * w1.z); p1.w = f2bf(h.w * w1.w);
  *(ushort4*)(X + base) = x;
  *(ushort4*)(P + base) = p0;
  *(ushort4*)(P + (size_t)B_ * L_ * D_ + base) = p1;
}

// ---------------------------------------------------------------------------
// Stage 2: 256x256 tile, t fused along M. DRIFT-PIPELINED schedule:
// 48 K-slices of BK=32; 4 LDS buffers x 32 KB (128 KB total); prefetch
// distance 2 slices; barrier only every 2 phases. Within a barrier window,
// reads use bufs {k,k+1}%4 and stages target {k+2,k+3}%4 (disjoint) ->
// waves may drift a full phase apart, overlapping the LDS pipe of one wave
// with the MFMA pipe of another (round-7 lockstep measured sum(LDS,MFMA)
// = 4200 cyc/64K-tile vs max = 2370). No lgkmcnt(0) drain: fragment reads
// are C-level, compiler emits fine-grained counted lgkmcnt per MFMA.
// Boundary WVM(0) drains loads issued >= 1 full phase earlier (L2-warm).
// Fragment geometry / swizzle / staging map / epilogue verbatim round-7
// (verified: 0 bank conflicts, absmax 0.0625).
// ---------------------------------------------------------------------------
__device__ __forceinline__ void gload16(const unsigned short* g, unsigned short* l) {
  __builtin_amdgcn_global_load_lds(
      (const __attribute__((address_space(1))) unsigned int*)g,
      (__attribute__((address_space(3))) unsigned int*)l, 16, 0, 0);
}

#define B0O 0
#define B1O 16384
#define B2O 32768
#define B3O 49152

__global__ __launch_bounds__(512, 2) void gemm_kernel(
    const unsigned short* __restrict__ X, const unsigned short* __restrict__ P,
    const float* __restrict__ bias, float2* __restrict__ out) {
  __shared__ unsigned short lds[65536];   // 128 KiB = 4 buffers x 16384 shorts

  const int tid = threadIdx.x;

  // ---- T1: XCD-aware bijective swizzle (256 % 8 == 0)
  const int id  = blockIdx.x;
  const int swz = (id & 7) * 32 + (id >> 3);
  const int bz  = swz >> 7;               // batch
  const int t2  = swz & 127;
  const int I0  = (t2 >> 3) * 128;        // 16 i-tiles
  const int J0  = (t2 & 7) * 256;         // 8 j-tiles

  const size_t planeB = (size_t)B_ * L_ * D_;

  // ---- staging: thread tid -> sub-block entry (row r = tid>>2, slot tid&3),
  // 16B each, LDS-linear. Source chunk inverse-swizzled:
  // c = (tid&3) ^ ((tid>>3)&3).
  const size_t gsrcOff = (size_t)(tid >> 2) * D_ +
                         (size_t)((((tid & 3) ^ ((tid >> 3) & 3))) * 8);
  const unsigned short* sA0 = P + (size_t)(bz * L_ + I0) * D_ + gsrcOff;   // P0
  const unsigned short* sA1 = sA0 + planeB;                                // P1
  const unsigned short* sB0 = X + (size_t)(bz * L_ + J0) * D_ + gsrcOff;   // X lo
  const unsigned short* sB1 = sB0 + (size_t)128 * D_;                      // X hi
  const int wuni = (tid >> 6) * 512;   // wave-uniform LDS base (shorts)

  // ---- compute geometry (16x16x32 frags; 8 waves = 2 wr x 4 wc)
  const int lane = tid & 63;
  const int w    = tid >> 6;
  const int wr   = w & 1;
  const int wc   = w >> 1;
  const int lr   = lane & 15;
  const int q    = lane >> 4;
  const int slot8 = ((q ^ ((lr >> 1) & 3)) * 8);   // read-side swizzled slot
  int aOff[8], bOff[4];
#pragma unroll
  for (int m = 0; m < 8; ++m)
    aOff[m] = (m >> 2) * 4096 + (wr * 64 + (m & 3) * 16 + lr) * 32;
#pragma unroll
  for (int n = 0; n < 4; ++n)
    bOff[n] = 8192 + (n >> 1) * 4096 + (wc * 32 + (n & 1) * 16 + lr) * 32;

  f32x4  acc[8][4] = {};
  bf16x8 aF[8], bF[4];

  // Buffer layout (shorts): buf + {A0:0, A1:4096, B0:8192, B1:12288};
  // each sub-block = 4096 shorts = 128 rows x 64 B.
#define STG4(NB, PN)                                                          \
  do {                                                                        \
    const size_t ko = (size_t)((PN) * 32);                                    \
    gload16(sA0 + ko, lds + (NB) + 0     + wuni);                             \
    gload16(sA1 + ko, lds + (NB) + 4096  + wuni);                             \
    gload16(sB0 + ko, lds + (NB) + 8192  + wuni);                             \
    gload16(sB1 + ko, lds + (NB) + 12288 + wuni);                             \
  } while (0)

#define RDALL(CB)                                                             \
  do {                                                                        \
    const unsigned short* base_ = lds + (CB) + slot8;                         \
    _Pragma("unroll") for (int m = 0; m < 8; ++m)                             \
      aF[m] = *(const bf16x8*)(base_ + aOff[m]);                              \
    _Pragma("unroll") for (int n = 0; n < 4; ++n)                             \
      bF[n] = *(const bf16x8*)(base_ + bOff[n]);                              \
  } while (0)

#define MMALL()                                                               \
  do {                                                                        \
    _Pragma("unroll") for (int m = 0; m < 8; ++m)                             \
      _Pragma("unroll") for (int n = 0; n < 4; ++n)                           \
        acc[m][n] = __builtin_amdgcn_mfma_f32_16x16x32_bf16(                  \
            aF[m], bF[n], acc[m][n], 0, 0, 0);                                \
  } while (0)

#define BNDRY()                                                               \
  do {                                                                        \
    asm volatile("s_waitcnt vmcnt(0)" ::: "memory");                          \
    __builtin_amdgcn_s_barrier();                                             \
    __builtin_amdgcn_sched_barrier(0);                                        \
  } while (0)

#define PRIO1() __builtin_amdgcn_s_setprio(1)
#define PRIO0() __builtin_amdgcn_s_setprio(0)

  // phase: read slice from CB, stage slice PN+2 into SB, 32 MFMAs.
  // No per-phase barrier, no lgkmcnt(0) drain (compiler inserts counted).
#define PH(CB, SB, PN)                                                        \
  do {                                                                        \
    RDALL(CB); STG4(SB, (PN) + 2);                                            \
    PRIO1(); MMALL(); PRIO0();                                                \
  } while (0)

#define PHNS(CB)                                                              \
  do {                                                                        \
    RDALL(CB);                                                                \
    PRIO1(); MMALL(); PRIO0();                                                \
  } while (0)

  // ---- prologue: slices 0,1 into buffers 0,1
  STG4(B0O, 0);
  STG4(B1O, 1);

  // ---- main loop: 11 iters x 4 phases = phases 0..43 (stages reach 45)
#pragma unroll 1
  for (int it = 0; it < 11; ++it) {
    const int p0 = 4 * it;
    BNDRY();                      // confirms slices p0, p0+1 staged
    PH(B0O, B2O, p0);             // phase p0:   read b0, stage p0+2 -> b2
    PH(B1O, B3O, p0 + 1);         // phase p0+1: read b1, stage p0+3 -> b3
    BNDRY();                      // confirms slices p0+2, p0+3
    PH(B2O, B0O, p0 + 2);         // read b2, stage p0+4 -> b0
    PH(B3O, B1O, p0 + 3);         // read b3, stage p0+5 -> b1
  }

  // ---- tail: phases 44..47
  BNDRY();                        // confirms 44, 45
  PH(B0O, B2O, 44);               // stage 46 -> b2
  PH(B1O, B3O, 45);               // stage 47 -> b3
  BNDRY();                        // confirms 46, 47
  PHNS(B2O);
  PHNS(B3O);

#undef PH
#undef PHNS
#undef BNDRY
#undef STG4
#undef RDALL
#undef MMALL

  // ---- epilogue (VERBATIM round-1/7): C/D col(j)=lane&15, row(i)=q*4+reg.
  // acc[m][.] (m<4) = t0, acc[m+4][.] = t1 at the SAME i -> dense float2.
  const float bias0 = bias[0], bias1 = bias[1];
#pragma unroll
  for (int m = 0; m < 4; ++m) {
#pragma unroll
    for (int r = 0; r < 4; ++r) {
      const int i = I0 + wr * 64 + m * 16 + q * 4 + r;
      float2* orow = out + (size_t)(bz * L_ + i) * L_;
#pragma unroll
      for (int n = 0; n < 4; ++n) {
        const int j = J0 + (n >> 1) * 128 + wc * 32 + (n & 1) * 16 + lr;
        float2 v;
        v.x = acc[m][n][r] + bias0;
        v.y = acc[m + 4][n][r] + bias1;
        orow[j] = v;
      }
    }
  }
}

extern "C" void kernel_launch(void* const* d_in, const int* in_sizes, int n_in,
                              void* d_out, int out_size, void* d_ws, size_t ws_size,
                              hipStream_t stream) {
  const float* hs   = (const float*)d_in[0];
  const float* W    = (const float*)d_in[1];
  const float* bias = (const float*)d_in[2];

  unsigned short* X = (unsigned short*)d_ws;                 // B*L*D bf16
  unsigned short* P = X + (size_t)B_ * L_ * D_;              // T*B*L*D bf16

  const int nconv = (B_ * L_ * D_ / 4) / 256;                // 6144 blocks
  conv_kernel<<<nconv, 256, 0, stream>>>(hs, W, X, P);

  gemm_kernel<<<256, 512, 0, stream>>>(X, P, bias, (float2*)d_out);
}